// Round 14
// baseline (138.919 us; speedup 1.0000x reference)
//
#include <hip/hip_runtime.h>

// KDE joint histogram via DIRECT LDS SCATTER-ACCUMULATE, FUSED w/ MANUAL
// PER-BATCH BARRIER (R24).
// joint[b,i,j] = sum_k qx[b,k,i]*qy[b,k,j], q = round(127*exp(-0.5 d^2)).
// Geometry = R19 (scan-optimal): NST=2 x NCH=32 x B=4 = 256 blocks, 1/CU
// (132KB LDS), BLOCK=1024. R23 lesson: hipLaunchCooperativeKernel broke
// graph capture (+32us) — the inter-dispatch-gap theory was never tested.
// R24 tests it with a REGULAR launch: after writing partials+ws2, the 64
// blocks of a batch meet at a padded per-batch atomic barrier (release
// fence -> arrive -> bounded spin -> acquire fence), then normalize and
// write out directly. SAFETY: on spin timeout blocks skip phase 2; an
// always-enqueued skip-tail checks the pass-count flag and redoes the old
// reduction iff the barrier failed (idempotent — passers wrote identical
// values). Counters memset to 0 each launch (2KB, graph-capturable).
// History: R17 reformulation (-9); R18 16 waves/CU (-5.8); R19 u64 packing
// NULL; R20 diagnostic: particle loop = 4us, rest is scaffolding/overhead;
// R21 NST=8 REGRESSED (wave-granular scan); R15: padded atomics only.

#define B_     4
#define N_     50000
#define M_     256
#define NCH    32                  // raw-K chunks (split-K partials)
#define NST    2                   // strips of 128 output rows
#define CHUNK  ((N_ + NCH - 1) / NCH)   // 1563
#define BLOCK  1024                // 16 waves/CU (grid 256 = 1 block/CU)
#define NWAVE  (BLOCK / 64)
#define GROWS  128
#define GCELLS (GROWS * M_)        // 32768 live u32 cells = 16384 u64 pairs
#define GP64   16384               // live u64 pairs
#define G64SZ  16576               // + dump scratch
#define CS2    0.72134752f         // 0.5*log2(e)
#define L127   6.9886847f          // log2(127)
#define SPIN   100000              // barrier spin bound (~20ms worst case)

#if __has_builtin(__builtin_amdgcn_exp2f)
  #define EXP2(t) __builtin_amdgcn_exp2f(t)
#else
  #define EXP2(t) exp2f(t)
#endif

__device__ __forceinline__ unsigned short bf16ru(float f) {  // round-half-up
    return (unsigned short)((__builtin_bit_cast(unsigned, f) + 0x8000u) >> 16);
}
__device__ __forceinline__ float bf2f(unsigned short u) {
    return __builtin_bit_cast(float, ((unsigned)u) << 16);
}

// ctrl layout (ints): arrive ctr for batch b at [b*32]; pass-count flag at
// [256 + b*32]. 128B padding -> each counter owns a cacheline (R15 lesson).

__global__ __launch_bounds__(BLOCK) void kde_fused(
    const float* __restrict__ xs, const float* __restrict__ ys,
    const float* __restrict__ bins, unsigned short* __restrict__ partial,
    float* __restrict__ ws2, int* __restrict__ ctrl, float* __restrict__ out)
{
    __shared__ __align__(16) unsigned long long G64[G64SZ];  // 132,608 B
    __shared__ float sred[NWAVE];
    __shared__ float snorm;
    __shared__ int   sok;

    const int tid   = threadIdx.x;
    const int strip = blockIdx.x;          // 0..NST-1: rows [strip*128, +128)
    const int chunk = blockIdx.y;          // 0..NCH-1: raw K segment
    const int b     = blockIdx.z;
    const int lane  = tid & 63;
    const int w     = tid >> 6;

    const float bin0  = bins[0];
    const float invbw = 1.0f / (bins[1] - bin0);
    const int   rlo   = strip * GROWS;

    // ---- phase 1a: zero the grid (incl. dump scratch) ----
    {
        uint4* gz = (uint4*)G64;
        const uint4 z4 = {0u, 0u, 0u, 0u};
        for (int t = tid; t < G64SZ / 2; t += BLOCK) gz[t] = z4;
    }
    __syncthreads();

    const int start = chunk * CHUNK;
    const int end   = (start + CHUNK < N_) ? (start + CHUNK) : N_;
    const float* xp = xs + (size_t)b * N_;
    const float* yp = ys + (size_t)b * N_;

    const unsigned dmp = (unsigned)(GP64 + lane);   // per-lane u64 dump slot

    // ---- phase 1b: scatter-accumulate (software-pipelined coord loads) ----
    int k = start + tid;
    float x = 3.0e30f, y = 3.0e30f;
    if (k < end) { x = xp[k]; y = yp[k]; }
    for (; k < end; k += BLOCK) {
        float xn = 3.0e30f, yn = 3.0e30f;
        if (k + BLOCK < end) { xn = xp[k + BLOCK]; yn = yp[k + BLOCK]; }

        const float ux  = (x - bin0) * invbw;
        const float uy  = (y - bin0) * invbw;
        const float stx = rintf(ux) - 3.0f;      // window rows rx..rx+6
        const float sty = rintf(uy) - 3.0f;
        const int rx = (int)stx;
        const int ry = (int)sty;

        if (rx + 6 >= rlo && rx < rlo + GROWS && ry + 6 >= 0 && ry < M_) {
            const float dx0 = ux - stx;          // in [2.5, 3.5]
            const float dy0 = uy - sty;
            unsigned qx[7], qy[7];
            #pragma unroll
            for (int j = 0; j < 7; ++j) {
                const float dx = dx0 - (float)j;
                const float dy = dy0 - (float)j;
                qx[j] = (unsigned)(int)(EXP2(fmaf(-CS2 * dx, dx, L127)) + 0.5f);
                qy[j] = (unsigned)(int)(EXP2(fmaf(-CS2 * dy, dy, L127)) + 0.5f);
            }
            // pack y window into 4 even-aligned column-pair u64s
            const int s  = ry & 1;
            const int pb0 = (ry - s) >> 1;
            const unsigned lo0 = s ? 0u    : qy[0], hi0 = s ? qy[0] : qy[1];
            const unsigned lo1 = s ? qy[1] : qy[2], hi1 = s ? qy[2] : qy[3];
            const unsigned lo2 = s ? qy[3] : qy[4], hi2 = s ? qy[4] : qy[5];
            const unsigned lo3 = s ? qy[5] : qy[6], hi3 = s ? qy[6] : 0u;
            unsigned long long ypk[4];
            ypk[0] = (unsigned long long)lo0 | ((unsigned long long)hi0 << 32);
            ypk[1] = (unsigned long long)lo1 | ((unsigned long long)hi1 << 32);
            ypk[2] = (unsigned long long)lo2 | ((unsigned long long)hi2 << 32);
            ypk[3] = (unsigned long long)lo3 | ((unsigned long long)hi3 << 32);
            unsigned pofs[4];
            #pragma unroll
            for (int t = 0; t < 4; ++t) {
                const int p = pb0 + t;
                pofs[t] = ((unsigned)p < 128u) ? (unsigned)p : 0x80000000u;
            }
            #pragma unroll
            for (int i = 0; i < 7; ++i) {
                const int rr = rx + i - rlo;
                const unsigned rbase =
                    ((unsigned)rr < (unsigned)GROWS) ? (unsigned)(rr << 7) : dmp;
                const unsigned long long wxi = (unsigned long long)qx[i];
                #pragma unroll
                for (int t = 0; t < 4; ++t) {
                    unsigned a = rbase + pofs[t];
                    a = ((int)a < 0) ? dmp : a;
                    atomicAdd(&G64[a], wxi * ypk[t]);    // ds_add_u64
                }
            }
        }
        x = xn; y = yn;
    }
    __syncthreads();                         // all waves' atomics complete

    // ---- phase 1c: i32 grid -> bf16 split-K partial + strip sum ----
    const unsigned int* Gv = (const unsigned int*)G64;
    unsigned short* pb = partial + (((size_t)chunk * B_ + b) << 16);
    float tsum = 0.f;
    #pragma unroll
    for (int rep = 0; rep < GCELLS / (BLOCK * 4); ++rep) {   // 8 reps
        const int cell = rep * (BLOCK * 4) + tid * 4;
        const uint4 gv = *(const uint4*)&Gv[cell];           // ds_read_b128
        const float f0 = (float)gv.x, f1 = (float)gv.y;
        const float f2 = (float)gv.z, f3 = (float)gv.w;
        tsum += (f0 + f1) + (f2 + f3);
        ushort4 o;
        o.x = bf16ru(f0); o.y = bf16ru(f1); o.z = bf16ru(f2); o.w = bf16ru(f3);
        const int r = cell >> 8;
        const int c = cell & (M_ - 1);
        *(ushort4*)&pb[(size_t)(rlo + r) * M_ + c] = o;
    }

    // ---- phase 1d: block sum -> ws2 slot ----
    #pragma unroll
    for (int off = 32; off; off >>= 1) tsum += __shfl_xor(tsum, off);
    if (lane == 0) sred[w] = tsum;
    __syncthreads();
    if (tid == 0) {
        float bsum = 0.f;
        #pragma unroll
        for (int i = 0; i < NWAVE; ++i) bsum += sred[i];
        ws2[(b * NCH + chunk) * NST + strip] = bsum;   // slot b*64+chunk*2+strip
    }
    __syncthreads();

    // ---- per-batch barrier: 64 blocks of batch b ----
    if (tid == 0) {
        __threadfence();                     // release: partials+ws2 visible
        atomicAdd(&ctrl[b * 32], 1);
        int ok = 0;
        for (int i = 0; i < SPIN; ++i) {
            if (__hip_atomic_load(&ctrl[b * 32], __ATOMIC_RELAXED,
                                  __HIP_MEMORY_SCOPE_AGENT) >= 64) { ok = 1; break; }
            __builtin_amdgcn_s_sleep(4);
        }
        sok = ok;
    }
    __syncthreads();
    if (!sok) return;                        // safety tail will finish
    __threadfence();                         // acquire: drop stale cache lines

    // ---- phase 2a: per-batch norm from this batch's 64 ws2 slots ----
    {
        float t = (tid < NST * NCH) ? ws2[(b << 6) + tid] : 0.f;
        if (w == 0) {
            #pragma unroll
            for (int off = 32; off; off >>= 1) t += __shfl_xor(t, off);
            if (lane == 0) snorm = t;
        }
        __syncthreads();
    }
    const float sc = 1.0f / (snorm + 1e-10f);

    // ---- phase 2b: one output float per thread (B*M*M threads total) ----
    const int fid = (((b * NCH + chunk) * NST + strip) << 10) + tid;
    const int cb = fid & 65535;              // cell within batch (fid>>16 == b)
    float a = 0.f;
    #pragma unroll
    for (int c = 0; c < NCH; ++c)            // same order as old tail
        a += bf2f(partial[(((size_t)c * B_ + b) << 16) + cb]);
    out[fid] = a * sc;

    if (tid == 0) atomicAdd(&ctrl[256 + b * 32], 1);   // pass-count flag
}

// Safety tail: no-op when the in-kernel barrier succeeded (flag==64).
__global__ __launch_bounds__(256) void kde_tail(
    const unsigned short* __restrict__ partial, const float* __restrict__ ws2,
    const int* __restrict__ ctrl, float* __restrict__ out)
{
    __shared__ float sred[4];
    __shared__ float snorm;
    const int tid = threadIdx.x;
    const int cellIdx = blockIdx.x * 256 + tid;     // float4 index, 16384/batch
    const int bb = cellIdx >> 14;                   // uniform per block
    const int cb = cellIdx & 16383;

    if (ctrl[256 + bb * 32] == 64) return;   // fused phase 2 completed batch

    float t = (tid < NST * NCH) ? ws2[bb * (NST * NCH) + tid] : 0.f;
    #pragma unroll
    for (int off = 32; off; off >>= 1) t += __shfl_xor(t, off);
    if ((tid & 63) == 0) sred[tid >> 6] = t;
    __syncthreads();
    if (tid == 0) snorm = sred[0] + sred[1] + sred[2] + sred[3];
    __syncthreads();
    const float nrm = snorm;

    float4 a = {0.f, 0.f, 0.f, 0.f};
    #pragma unroll
    for (int c = 0; c < NCH; ++c) {
        const ushort4 v = *(const ushort4*)(partial +
            (((size_t)c * B_ + bb) << 16) + (size_t)cb * 4);
        a.x += bf2f(v.x); a.y += bf2f(v.y); a.z += bf2f(v.z); a.w += bf2f(v.w);
    }
    const float sc = 1.0f / (nrm + 1e-10f);
    a.x *= sc; a.y *= sc; a.z *= sc; a.w *= sc;
    ((float4*)out)[cellIdx] = a;
}

extern "C" void kernel_launch(void* const* d_in, const int* in_sizes, int n_in,
                              void* d_out, int out_size, void* d_ws, size_t ws_size,
                              hipStream_t stream)
{
    const float* xs   = (const float*)d_in[0];
    const float* ys   = (const float*)d_in[1];
    const float* bins = (const float*)d_in[2];
    float* out = (float*)d_out;

    unsigned short* partial = (unsigned short*)d_ws;        // 16.8 MB bf16
    const size_t PSZ = (size_t)NCH * B_ * M_ * M_ * sizeof(unsigned short);
    float* ws2  = (float*)((char*)d_ws + PSZ);              // 256 f32
    int*   ctrl = (int*)((char*)d_ws + PSZ + 4096);         // padded ctr+flag

    hipMemsetAsync(ctrl, 0, 2048, stream);
    kde_fused<<<dim3(NST, NCH, B_), dim3(BLOCK), 0, stream>>>(
        xs, ys, bins, partial, ws2, ctrl, out);
    kde_tail<<<dim3(B_ * M_ * M_ / (4 * 256)), dim3(256), 0, stream>>>(
        partial, ws2, ctrl, out);
}

// Round 15
// 75.339 us; speedup vs baseline: 1.8439x; 1.8439x over previous
//
#include <hip/hip_runtime.h>

// KDE joint histogram via DIRECT LDS SCATTER-ACCUMULATE (R25 = R19 revert;
// best verified config, 75.1us).
// joint[b,i,j] = sum_k qx[b,k,i]*qy[b,k,j], q = round(127*exp(-0.5 d^2))
// (i8 support ±3.33 bins -> 7-bin window; 127^2 scale cancels in norm).
// Each block owns a 128x256 output strip as an i32 LDS grid and scans a raw
// K-chunk; column-PAIR packed ds_add_u64 atomics (28/particle). Carry-safe:
// per-chunk cell sums <= 1563*127^2 ~ 25M < 2^31. Deterministic (int adds).
// bf16 split-K partials -> tail reduce+normalize.
// FINAL ACCOUNTING (R20/R24 diagnostics): fill 44us (harness, immovable) +
// particle loop 4us (R20 repeat-diag) + staging/partial/tail ~9us (HBM BW)
// + ~14us launch/graph overhead OUTSIDE kernels (R24: sum-of-dispatches vs
// total). Structural attempts on the overhead ALL REGRESSED:
//   R21 NST=8 re-split: +4us (scan is wave-granular: NST*B*N).
//   R23 hipLaunchCooperativeKernel fusion: +32us (breaks graph capture).
//   R24 manual per-batch barrier fusion: +64us (fused kernel 79.5us, VALU
//     6us — per-block device-scope release/acquire __threadfence = L2
//     writeback/invalidate walks x512 + cross-XCD hot-line polling; the
//     kernel-boundary drain does ONE pipelined L2 flush instead).
// Earlier: R15 single-cacheline global atomics = 145us cross-XCD ping-pong;
// R16 sparse-GEMM net-neutral; R17 reformulation -9us; R18 16 waves/CU
// -5.8us; R19 u64 packing NULL (loop already tiny).

#define B_     4
#define N_     50000
#define M_     256
#define NCH    32                  // raw-K chunks (split-K partials)
#define NST    2                   // strips of 128 output rows
#define CHUNK  ((N_ + NCH - 1) / NCH)   // 1563
#define BLOCK  1024                // 16 waves/CU (grid 256 = 1 block/CU)
#define NWAVE  (BLOCK / 64)
#define GROWS  128
#define GCELLS (GROWS * M_)        // 32768 live u32 cells = 16384 u64 pairs
#define GP64   16384               // live u64 pairs
#define G64SZ  16576               // + dump scratch (max 16384+63+127)
#define CS2    0.72134752f         // 0.5*log2(e)
#define L127   6.9886847f          // log2(127)

#if __has_builtin(__builtin_amdgcn_exp2f)
  #define EXP2(t) __builtin_amdgcn_exp2f(t)
#else
  #define EXP2(t) exp2f(t)
#endif

__device__ __forceinline__ unsigned short bf16ru(float f) {  // round-half-up
    return (unsigned short)((__builtin_bit_cast(unsigned, f) + 0x8000u) >> 16);
}
__device__ __forceinline__ float bf2f(unsigned short u) {
    return __builtin_bit_cast(float, ((unsigned)u) << 16);
}

__global__ __launch_bounds__(BLOCK) void kde_accum(
    const float* __restrict__ xs, const float* __restrict__ ys,
    const float* __restrict__ bins, unsigned short* __restrict__ partial,
    float* __restrict__ ws2, int wide)
{
    __shared__ __align__(16) unsigned long long G64[G64SZ];  // 132,608 B
    __shared__ float sred[NWAVE];

    const int tid   = threadIdx.x;
    const int strip = blockIdx.x;          // 0..NST-1: rows [strip*128, +128)
    const int chunk = blockIdx.y;          // 0..NCH-1: raw K segment
    const int b     = blockIdx.z;
    const int lane  = tid & 63;
    const int w     = tid >> 6;

    const float bin0  = bins[0];
    const float invbw = 1.0f / (bins[1] - bin0);
    const int   rlo   = strip * GROWS;

    // ---- zero the grid (incl. dump scratch) ----
    {
        uint4* gz = (uint4*)G64;
        const uint4 z4 = {0u, 0u, 0u, 0u};
        for (int t = tid; t < G64SZ / 2; t += BLOCK) gz[t] = z4;
    }
    __syncthreads();

    const int start = chunk * CHUNK;
    const int end   = (start + CHUNK < N_) ? (start + CHUNK) : N_;
    const float* xp = xs + (size_t)b * N_;
    const float* yp = ys + (size_t)b * N_;

    const unsigned dmp = (unsigned)(GP64 + lane);   // per-lane u64 dump slot

    // software-pipelined particle loop (prefetch next round's coords)
    int k = start + tid;
    float x = 3.0e30f, y = 3.0e30f;
    if (k < end) { x = xp[k]; y = yp[k]; }
    for (; k < end; k += BLOCK) {
        float xn = 3.0e30f, yn = 3.0e30f;
        if (k + BLOCK < end) { xn = xp[k + BLOCK]; yn = yp[k + BLOCK]; }

        const float ux  = (x - bin0) * invbw;
        const float uy  = (y - bin0) * invbw;
        const float stx = rintf(ux) - 3.0f;      // window rows rx..rx+6
        const float sty = rintf(uy) - 3.0f;
        const int rx = (int)stx;
        const int ry = (int)sty;

        // active iff x-window intersects this strip AND y-window hits grid
        if (rx + 6 >= rlo && rx < rlo + GROWS && ry + 6 >= 0 && ry < M_) {
            const float dx0 = ux - stx;          // in [2.5, 3.5]
            const float dy0 = uy - sty;
            unsigned qx[7], qy[7];
            #pragma unroll
            for (int j = 0; j < 7; ++j) {
                const float dx = dx0 - (float)j;
                const float dy = dy0 - (float)j;
                qx[j] = (unsigned)(int)(EXP2(fmaf(-CS2 * dx, dx, L127)) + 0.5f);
                qy[j] = (unsigned)(int)(EXP2(fmaf(-CS2 * dy, dy, L127)) + 0.5f);
            }
            // ---- pack y window into 4 even-aligned column-pair u64s ----
            const int s  = ry & 1;               // parity (per-lane)
            const int pb0 = (ry - s) >> 1;       // first pair index (may be <0)
            const unsigned lo0 = s ? 0u    : qy[0], hi0 = s ? qy[0] : qy[1];
            const unsigned lo1 = s ? qy[1] : qy[2], hi1 = s ? qy[2] : qy[3];
            const unsigned lo2 = s ? qy[3] : qy[4], hi2 = s ? qy[4] : qy[5];
            const unsigned lo3 = s ? qy[5] : qy[6], hi3 = s ? qy[6] : 0u;
            unsigned long long ypk[4];
            ypk[0] = (unsigned long long)lo0 | ((unsigned long long)hi0 << 32);
            ypk[1] = (unsigned long long)lo1 | ((unsigned long long)hi1 << 32);
            ypk[2] = (unsigned long long)lo2 | ((unsigned long long)hi2 << 32);
            ypk[3] = (unsigned long long)lo3 | ((unsigned long long)hi3 << 32);
            unsigned pofs[4];
            #pragma unroll
            for (int t = 0; t < 4; ++t) {
                const int p = pb0 + t;           // pair col index
                pofs[t] = ((unsigned)p < 128u) ? (unsigned)p : 0x80000000u;
            }
            #pragma unroll
            for (int i = 0; i < 7; ++i) {
                const int rr = rx + i - rlo;
                const unsigned rbase =
                    ((unsigned)rr < (unsigned)GROWS) ? (unsigned)(rr << 7) : dmp;
                const unsigned long long wxi = (unsigned long long)qx[i];
                #pragma unroll
                for (int t = 0; t < 4; ++t) {
                    unsigned a = rbase + pofs[t];
                    a = ((int)a < 0) ? dmp : a;  // invalid pair -> dump slot
                    atomicAdd(&G64[a], wxi * ypk[t]);    // ds_add_u64
                }
            }
        }
        x = xn; y = yn;
    }
    __syncthreads();                         // all waves' atomics complete

    // ---- epilogue: i32 grid -> bf16 split-K partial + strip sum ----
    // u32 view of G64: index r*256+c == row-major strip layout.
    const unsigned int* Gv = (const unsigned int*)G64;
    unsigned short* pb = partial + (((size_t)chunk * B_ + b) << 16);
    float tsum = 0.f;
    #pragma unroll
    for (int rep = 0; rep < GCELLS / (BLOCK * 4); ++rep) {   // 8 reps
        const int cell = rep * (BLOCK * 4) + tid * 4;
        const uint4 gv = *(const uint4*)&Gv[cell];           // ds_read_b128
        const float f0 = (float)gv.x, f1 = (float)gv.y;
        const float f2 = (float)gv.z, f3 = (float)gv.w;
        tsum += (f0 + f1) + (f2 + f3);
        ushort4 o;
        o.x = bf16ru(f0); o.y = bf16ru(f1); o.z = bf16ru(f2); o.w = bf16ru(f3);
        const int r = cell >> 8;             // strip-local row
        const int c = cell & (M_ - 1);       // col (multiple of 4)
        *(ushort4*)&pb[(size_t)(rlo + r) * M_ + c] = o;
    }

    // ---- block sum -> ws2 ----
    #pragma unroll
    for (int off = 32; off; off >>= 1) tsum += __shfl_xor(tsum, off);
    if (lane == 0) sred[w] = tsum;
    __syncthreads();
    if (tid == 0) {
        float bsum = 0.f;
        #pragma unroll
        for (int i = 0; i < NWAVE; ++i) bsum += sred[i];
        if (wide) {
            const int bid = (b * NCH + chunk) * NST + strip;   // < 256
            ws2[bid] = bsum;
        } else {
            atomicAdd(&ws2[b], bsum);
        }
    }
}

__global__ __launch_bounds__(256) void kde_tail(
    const unsigned short* __restrict__ partial, const float* __restrict__ ws2,
    float* __restrict__ out, int wide)
{
    __shared__ float sred[4];
    __shared__ float snorm;
    const int tid = threadIdx.x;
    const int cellIdx = blockIdx.x * 256 + tid;     // float4 index, 16384/batch
    const int bb = cellIdx >> 14;                   // uniform per block
    const int cb = cellIdx & 16383;

    float nrm;
    if (wide) {
        float t = (tid < NCH * NST) ? ws2[bb * (NCH * NST) + tid] : 0.f;
        #pragma unroll
        for (int off = 32; off; off >>= 1) t += __shfl_xor(t, off);
        if ((tid & 63) == 0) sred[tid >> 6] = t;
        __syncthreads();
        if (tid == 0) snorm = sred[0] + sred[1] + sred[2] + sred[3];
        __syncthreads();
        nrm = snorm;
    } else {
        nrm = ws2[bb];
    }

    float4 a = {0.f, 0.f, 0.f, 0.f};
    #pragma unroll
    for (int c = 0; c < NCH; ++c) {
        const ushort4 v = *(const ushort4*)(partial +
            (((size_t)c * B_ + bb) << 16) + (size_t)cb * 4);
        a.x += bf2f(v.x); a.y += bf2f(v.y); a.z += bf2f(v.z); a.w += bf2f(v.w);
    }
    // i8 scale (127^2) cancels: both partials and nrm carry it.
    const float sc = 1.0f / (nrm + 1e-10f);
    a.x *= sc; a.y *= sc; a.z *= sc; a.w *= sc;
    ((float4*)out)[cellIdx] = a;
}

extern "C" void kernel_launch(void* const* d_in, const int* in_sizes, int n_in,
                              void* d_out, int out_size, void* d_ws, size_t ws_size,
                              hipStream_t stream)
{
    const float* xs   = (const float*)d_in[0];
    const float* ys   = (const float*)d_in[1];
    const float* bins = (const float*)d_in[2];
    float* out = (float*)d_out;

    unsigned short* partial = (unsigned short*)d_ws;        // 16.8 MB bf16
    const size_t PSZ = (size_t)NCH * B_ * M_ * M_ * sizeof(unsigned short);
    float* ws2 = (float*)((char*)d_ws + PSZ);               // 256 f32 (wide)

    const int wide = (ws_size >= PSZ + 4096) ? 1 : 0;
    if (!wide) hipMemsetAsync(ws2, 0, 4 * sizeof(float), stream);

    kde_accum<<<dim3(NST, NCH, B_), dim3(BLOCK), 0, stream>>>(
        xs, ys, bins, partial, ws2, wide);
    kde_tail<<<dim3(B_ * M_ * M_ / (4 * 256)), dim3(256), 0, stream>>>(
        partial, ws2, out, wide);
}